// Round 6
// baseline (241.270 us; speedup 1.0000x reference)
//
#include <hip/hip_runtime.h>
#include <cstdint>

// Problem constants
#define BB 4
#define SS 2048
#define HH 1024
#define NHH 16
#define HDD 64
// M = BB*SS = 8192

typedef __bf16 bf16x8 __attribute__((ext_vector_type(8)));
typedef float f32x4 __attribute__((ext_vector_type(4)));
typedef unsigned short u16x8 __attribute__((ext_vector_type(8)));

__device__ __forceinline__ unsigned short f2b(float f) {
    unsigned int u = __float_as_uint(f);
    u += 0x7fffu + ((u >> 16) & 1u);   // round-to-nearest-even
    return (unsigned short)(u >> 16);
}

__device__ __forceinline__ void gload_lds16(const void* g, void* l) {
    __builtin_amdgcn_global_load_lds(
        (const __attribute__((address_space(1))) void*)g,
        (__attribute__((address_space(3))) void*)l, 16, 0, 0);
}

// ---------------- fp32 -> bf16 conversion ----------------
__global__ void cvt_bf16(const float* __restrict__ in,
                         unsigned short* __restrict__ out, long n) {
    long i = ((long)blockIdx.x * blockDim.x + threadIdx.x) * 4;
    long stride = (long)gridDim.x * blockDim.x * 4;
    for (; i < n; i += stride) {
        float4 v = *reinterpret_cast<const float4*>(in + i);
        ushort4 o;
        o.x = f2b(v.x); o.y = f2b(v.y); o.z = f2b(v.z); o.w = f2b(v.w);
        *reinterpret_cast<ushort4*>(out + i) = o;
    }
}

// 4 weight matrices (each HH*HH), outputs contiguous at out + y*HH*HH
__global__ void cvt_w4(const float* __restrict__ w0, const float* __restrict__ w1,
                       const float* __restrict__ w2, const float* __restrict__ w3,
                       unsigned short* __restrict__ out) {
    const float* s = blockIdx.y == 0 ? w0 : blockIdx.y == 1 ? w1 : blockIdx.y == 2 ? w2 : w3;
    unsigned short* o = out + (size_t)blockIdx.y * ((size_t)HH * HH);
    long n = (long)HH * HH;
    long stride = (long)gridDim.x * blockDim.x * 4;
    for (long i = ((long)blockIdx.x * blockDim.x + threadIdx.x) * 4; i < n; i += stride) {
        float4 v = *reinterpret_cast<const float4*>(s + i);
        ushort4 w;
        w.x = f2b(v.x); w.y = f2b(v.y); w.z = f2b(v.z); w.w = f2b(v.w);
        *reinterpret_cast<ushort4*>(o + i) = w;
    }
}

// ---------------- fused QKV GEMM (XCD-chunked, rows-fastest) ----------------
// A[8192][1024] bf16; Bqkv[3072][1024] bf16 (Wq,Wk,Wv stacked).
// 1536 workgroups: xcd = wg&7 owns chunk of 192 = 3 col panels x 64 row panels,
// rows fastest -> per-XCD B working set 768KB (L2-resident), A streamed.
__global__ __launch_bounds__(256) void gemm_qkv(
    const unsigned short* __restrict__ A,
    const unsigned short* __restrict__ Bqkv,
    const float* __restrict__ bq, const float* __restrict__ bk,
    const float* __restrict__ bv,
    unsigned short* __restrict__ Qo, unsigned short* __restrict__ Ko,
    unsigned short* __restrict__ Vto)
{
    __shared__ alignas(16) unsigned short Al[128][32];
    __shared__ alignas(16) unsigned short Bl[128][32];

    const int tid = threadIdx.x;
    const int lane = tid & 63;
    const int wid  = tid >> 6;
    const int wm = wid >> 1, wn = wid & 1;
    const int l15 = lane & 15, g = lane >> 4;

    // bijective XCD chunk swizzle: nwg=1536, chunk=192
    const int wg = blockIdx.x;
    const int L = (wg & 7) * 192 + (wg >> 3);
    const int row0 = (L & 63) * 128;          // row panel, fastest
    const int col0 = (L >> 6) * 128;          // col panel 0..23
    const int nb = col0 >> 10;                // 0:Q 1:K 2:V (uniform per block)
    const int cbase = col0 & 1023;
    const float* bias = nb == 0 ? bq : nb == 1 ? bk : bv;
    const int K = HH;

    f32x4 acc[4][4];
#pragma unroll
    for (int i = 0; i < 4; i++)
#pragma unroll
        for (int j = 0; j < 4; j++) acc[i][j] = (f32x4)0.0f;

    const int off0 = tid * 16;
    const int r0s = off0 >> 6, cb0 = off0 & 63;
    const int off1 = off0 + 4096;
    const int r1s = off1 >> 6, cb1 = off1 & 63;

    for (int k0 = 0; k0 < K; k0 += 32) {
        const char* gA = (const char*)(A + (size_t)row0 * K + k0);
        const char* gB = (const char*)(Bqkv + (size_t)col0 * K + k0);
        char* lA = (char*)&Al[0][0] + wid * 1024;
        char* lB = (char*)&Bl[0][0] + wid * 1024;
        gload_lds16(gA + (size_t)r0s * (K * 2) + cb0, lA);
        gload_lds16(gA + (size_t)r1s * (K * 2) + cb1, lA + 4096);
        gload_lds16(gB + (size_t)r0s * (K * 2) + cb0, lB);
        gload_lds16(gB + (size_t)r1s * (K * 2) + cb1, lB + 4096);
        __syncthreads();

        bf16x8 af[4], bf[4];
#pragma unroll
        for (int i = 0; i < 4; i++)
            af[i] = *reinterpret_cast<const bf16x8*>(&Al[wm * 64 + i * 16 + l15][g * 8]);
#pragma unroll
        for (int j = 0; j < 4; j++)
            bf[j] = *reinterpret_cast<const bf16x8*>(&Bl[wn * 64 + j * 16 + l15][g * 8]);
        __builtin_amdgcn_s_setprio(1);
#pragma unroll
        for (int i = 0; i < 4; i++)
#pragma unroll
            for (int j = 0; j < 4; j++)
                acc[i][j] = __builtin_amdgcn_mfma_f32_16x16x32_bf16(af[i], bf[j], acc[i][j], 0, 0, 0);
        __builtin_amdgcn_s_setprio(0);
        __syncthreads();
    }

#pragma unroll
    for (int i = 0; i < 4; i++) {
#pragma unroll
        for (int j = 0; j < 4; j++) {
#pragma unroll
            for (int r = 0; r < 4; r++) {
                int row = row0 + wm * 64 + i * 16 + g * 4 + r;
                int col = cbase + wn * 64 + j * 16 + l15;
                float v = acc[i][j][r] + bias[col];
                if (nb == 0) {
                    Qo[(size_t)row * HH + col] = f2b(v);
                } else if (nb == 1) {
                    Ko[(size_t)row * HH + col] = f2b(v);
                } else {
                    int b = row >> 11;
                    int s = row & (SS - 1);
                    int s6 = s & 63;
                    int sp6 = (s6 & 0x23) | ((s6 & 0x0C) << 1) | ((s6 & 0x10) >> 2);
                    int head = col >> 6;
                    int d = col & (HDD - 1);
                    size_t idx = (((size_t)b * NHH + head) * HDD + d) * SS + (s & ~63) + sp6;
                    Vto[idx] = f2b(v);
                }
            }
        }
    }
}

// ---------------- out-projection GEMM (fp32 out, XCD-chunked) ----------------
__global__ __launch_bounds__(256) void gemm_out(
    const unsigned short* __restrict__ A,   // [M][K] bf16
    const unsigned short* __restrict__ Bm,  // [N][K] bf16
    const float* __restrict__ bias,         // [N]
    float* __restrict__ Cout,
    int M, int N, int K)
{
    __shared__ alignas(16) unsigned short Al[128][32];
    __shared__ alignas(16) unsigned short Bl[128][32];

    const int tid = threadIdx.x;
    const int lane = tid & 63;
    const int wid  = tid >> 6;
    const int wm = wid >> 1, wn = wid & 1;
    const int l15 = lane & 15, g = lane >> 4;

    // bijective XCD chunk swizzle: nwg=512, chunk=64 -> 1 col panel per XCD
    const int wg = blockIdx.x;
    const int L = (wg & 7) * 64 + (wg >> 3);
    const int row0 = (L & 63) * 128;
    const int col0 = (L >> 6) * 128;

    f32x4 acc[4][4];
#pragma unroll
    for (int i = 0; i < 4; i++)
#pragma unroll
        for (int j = 0; j < 4; j++) acc[i][j] = (f32x4)0.0f;

    const int off0 = tid * 16;
    const int r0s = off0 >> 6, cb0 = off0 & 63;
    const int off1 = off0 + 4096;
    const int r1s = off1 >> 6, cb1 = off1 & 63;

    for (int k0 = 0; k0 < K; k0 += 32) {
        const char* gA = (const char*)(A + (size_t)row0 * K + k0);
        const char* gB = (const char*)(Bm + (size_t)col0 * K + k0);
        char* lA = (char*)&Al[0][0] + wid * 1024;
        char* lB = (char*)&Bl[0][0] + wid * 1024;
        gload_lds16(gA + (size_t)r0s * (K * 2) + cb0, lA);
        gload_lds16(gA + (size_t)r1s * (K * 2) + cb1, lA + 4096);
        gload_lds16(gB + (size_t)r0s * (K * 2) + cb0, lB);
        gload_lds16(gB + (size_t)r1s * (K * 2) + cb1, lB + 4096);
        __syncthreads();

        bf16x8 af[4], bf[4];
#pragma unroll
        for (int i = 0; i < 4; i++)
            af[i] = *reinterpret_cast<const bf16x8*>(&Al[wm * 64 + i * 16 + l15][g * 8]);
#pragma unroll
        for (int j = 0; j < 4; j++)
            bf[j] = *reinterpret_cast<const bf16x8*>(&Bl[wn * 64 + j * 16 + l15][g * 8]);
        __builtin_amdgcn_s_setprio(1);
#pragma unroll
        for (int i = 0; i < 4; i++)
#pragma unroll
            for (int j = 0; j < 4; j++)
                acc[i][j] = __builtin_amdgcn_mfma_f32_16x16x32_bf16(af[i], bf[j], acc[i][j], 0, 0, 0);
        __builtin_amdgcn_s_setprio(0);
        __syncthreads();
    }

#pragma unroll
    for (int i = 0; i < 4; i++) {
#pragma unroll
        for (int j = 0; j < 4; j++) {
#pragma unroll
            for (int r = 0; r < 4; r++) {
                int row = row0 + wm * 64 + i * 16 + g * 4 + r;
                int col = col0 + wn * 64 + j * 16 + l15;
                Cout[(size_t)row * N + col] = acc[i][j][r] + bias[col];
            }
        }
    }
}

// ---------------- Flash attention (swapped QK^T, fragment-linear LDS) ----------------
// Q,K: bf16 [B*S][H];  Vt: bf16 [B][NH][HD][S] key-permuted;  Oa: bf16 [B*S][H]
// 1024 workgroups, XCD-chunked: each XCD owns 8 (b,h) pairs x 16 q-tiles
// contiguous -> that head's K/V (512KB) stays L2-resident.
__global__ __launch_bounds__(256, 4) void attn_kernel(
    const unsigned short* __restrict__ Q,
    const unsigned short* __restrict__ K,
    const unsigned short* __restrict__ Vt,
    unsigned short* __restrict__ Oa)
{
    __shared__ alignas(16) unsigned short Kf[2][8][64][8];
    __shared__ alignas(16) unsigned short Vf[2][8][64][8];

    const int tid = threadIdx.x;
    const int lane = tid & 63;
    const int wid  = tid >> 6;
    const int l15 = lane & 15, g = lane >> 4;

    // bijective XCD chunk swizzle: nwg=1024, chunk=128; q-tile fastest
    const int wg = blockIdx.x;
    const int L = (wg & 7) * 128 + (wg >> 3);
    const int qt = L & 15;
    const int bh = L >> 4;
    const int b  = bh >> 4;
    const int h  = bh & 15;
    const int q0 = qt * 128;
    const int qA = q0 + wid * 32;       // wave handles q-cols qA..+15 (A), qA+16..+31 (B)

    // Q as B-fragments, prescaled into log2 domain
    const float qs = 0.125f * 1.44269504088896f;
    const unsigned short* qpA = Q + (size_t)(b * SS + qA + l15) * HH + h * HDD + g * 8;
    const unsigned short* qpB = qpA + (size_t)16 * HH;
    u16x8 ra0 = *reinterpret_cast<const u16x8*>(qpA);
    u16x8 ra1 = *reinterpret_cast<const u16x8*>(qpA + 32);
    u16x8 rb0 = *reinterpret_cast<const u16x8*>(qpB);
    u16x8 rb1 = *reinterpret_cast<const u16x8*>(qpB + 32);
#pragma unroll
    for (int j = 0; j < 8; j++) {
        ra0[j] = f2b(__uint_as_float((unsigned)ra0[j] << 16) * qs);
        ra1[j] = f2b(__uint_as_float((unsigned)ra1[j] << 16) * qs);
        rb0[j] = f2b(__uint_as_float((unsigned)rb0[j] << 16) * qs);
        rb1[j] = f2b(__uint_as_float((unsigned)rb1[j] << 16) * qs);
    }
    const bf16x8 qa0 = __builtin_bit_cast(bf16x8, ra0);
    const bf16x8 qa1 = __builtin_bit_cast(bf16x8, ra1);
    const bf16x8 qb0 = __builtin_bit_cast(bf16x8, rb0);
    const bf16x8 qb1 = __builtin_bit_cast(bf16x8, rb1);

    u16x8 ou;
#pragma unroll
    for (int j = 0; j < 8; j++) ou[j] = 0x3F80;   // bf16 1.0
    const bf16x8 ones8 = __builtin_bit_cast(bf16x8, ou);
    const f32x4 zero4 = (f32x4)0.0f;

    f32x4 acc_a[4], acc_b[4];
#pragma unroll
    for (int dn = 0; dn < 4; dn++) { acc_a[dn] = zero4; acc_b[dn] = zero4; }
    float m_a = -INFINITY, m_b = -INFINITY, l_a = 0.f, l_b = 0.f;

    // staging geometry: thread holds row srow, 8-short units d0a and d0a+1
    const int srow = tid >> 2;            // 0..63 (K: key row; V: d row)
    const int d0a  = (tid & 3) * 2;       // unit index 0,2,4,6
    const int sfrag = ((srow >> 4) << 1) + (d0a >> 2);
    const int sslot = (srow & 15) | ((d0a & 3) << 4);

    const unsigned short* gK = K  + (size_t)(b * SS + srow) * HH + h * HDD + d0a * 8;
    const unsigned short* gV = Vt + (((size_t)b * NHH + h) * HDD + srow) * SS + d0a * 8;

    int4 kr0, kr1, vr0, vr1;

    auto stage_write = [&](int buf) {
        unsigned short* pk = &Kf[buf][sfrag][0][0] + sslot * 8;
        unsigned short* pv = &Vf[buf][sfrag][0][0] + sslot * 8;
        *reinterpret_cast<int4*>(pk)       = kr0;
        *reinterpret_cast<int4*>(pk + 128) = kr1;   // slot+16
        *reinterpret_cast<int4*>(pv)       = vr0;
        *reinterpret_cast<int4*>(pv + 128) = vr1;
    };

    // prologue: tile 0
    kr0 = *reinterpret_cast<const int4*>(gK);
    kr1 = *reinterpret_cast<const int4*>(gK + 8);
    vr0 = *reinterpret_cast<const int4*>(gV);
    vr1 = *reinterpret_cast<const int4*>(gV + 8);
    stage_write(0);
    gK += (size_t)64 * HH;
    gV += 64;
    __syncthreads();

    const int NT = SS / 64;
    int cur = 0;

    for (int kt = 0; kt < NT; kt++) {
        if (kt + 1 < NT) {   // issue next tile's loads; land in regs across compute
            kr0 = *reinterpret_cast<const int4*>(gK);
            kr1 = *reinterpret_cast<const int4*>(gK + 8);
            vr0 = *reinterpret_cast<const int4*>(gV);
            vr1 = *reinterpret_cast<const int4*>(gV + 8);
            gK += (size_t)64 * HH;
            gV += 64;
        }

        // ---- QK^T cluster: C[key][q], K-frags read once, shared by A and B ----
        f32x4 sa[4], sb[4];
        __builtin_amdgcn_s_setprio(1);
#pragma unroll
        for (int n = 0; n < 4; n++) {
            bf16x8 kf0 = *reinterpret_cast<const bf16x8*>(&Kf[cur][n * 2 + 0][lane][0]);
            bf16x8 kf1 = *reinterpret_cast<const bf16x8*>(&Kf[cur][n * 2 + 1][lane][0]);
            sa[n] = __builtin_amdgcn_mfma_f32_16x16x32_bf16(kf0, qa0, zero4, 0, 0, 0);
            sa[n] = __builtin_amdgcn_mfma_f32_16x16x32_bf16(kf1, qa1, sa[n], 0, 0, 0);
            sb[n] = __builtin_amdgcn_mfma_f32_16x16x32_bf16(kf0, qb0, zero4, 0, 0, 0);
            sb[n] = __builtin_amdgcn_mfma_f32_16x16x32_bf16(kf1, qb1, sb[n], 0, 0, 0);
        }
        __builtin_amdgcn_s_setprio(0);

        // ---- softmax A (sa dies into pa), then softmax B ----
        bf16x8 pa0, pa1, pb0, pb1;
        {
            float u0 = fmaxf(fmaxf(sa[0][0], sa[0][1]), fmaxf(sa[0][2], sa[0][3]));
            float u1 = fmaxf(fmaxf(sa[1][0], sa[1][1]), fmaxf(sa[1][2], sa[1][3]));
            float u2 = fmaxf(fmaxf(sa[2][0], sa[2][1]), fmaxf(sa[2][2], sa[2][3]));
            float u3 = fmaxf(fmaxf(sa[3][0], sa[3][1]), fmaxf(sa[3][2], sa[3][3]));
            float mt = fmaxf(fmaxf(u0, u1), fmaxf(u2, u3));
            mt = fmaxf(mt, __shfl_xor(mt, 16));
            mt = fmaxf(mt, __shfl_xor(mt, 32));
            if (!__all(mt - m_a <= 8.0f)) {
                float mnew = fmaxf(m_a, mt);
                float scl = __builtin_amdgcn_exp2f(m_a - mnew);
                m_a = mnew; l_a *= scl;
#pragma unroll
                for (int dn = 0; dn < 4; dn++)
#pragma unroll
                    for (int r = 0; r < 4; r++) acc_a[dn][r] *= scl;
            }
            float p[4][4];
#pragma unroll
            for (int n = 0; n < 4; n++)
#pragma unroll
                for (int r = 0; r < 4; r++) p[n][r] = __builtin_amdgcn_exp2f(sa[n][r] - m_a);
#pragma unroll
            for (int j = 0; j < 8; j++) {
                pa0[j] = (__bf16)p[j >> 2][j & 3];
                pa1[j] = (__bf16)p[2 + (j >> 2)][j & 3];
            }
        }
        {
            float u0 = fmaxf(fmaxf(sb[0][0], sb[0][1]), fmaxf(sb[0][2], sb[0][3]));
            float u1 = fmaxf(fmaxf(sb[1][0], sb[1][1]), fmaxf(sb[1][2], sb[1][3]));
            float u2 = fmaxf(fmaxf(sb[2][0], sb[2][1]), fmaxf(sb[2][2], sb[2][3]));
            float u3 = fmaxf(fmaxf(sb[3][0], sb[3][1]), fmaxf(sb[3][2], sb[3][3]));
            float mt = fmaxf(fmaxf(u0, u1), fmaxf(u2, u3));
            mt = fmaxf(mt, __shfl_xor(mt, 16));
            mt = fmaxf(mt, __shfl_xor(mt, 32));
            if (!__all(mt - m_b <= 8.0f)) {
                float mnew = fmaxf(m_b, mt);
                float scl = __builtin_amdgcn_exp2f(m_b - mnew);
                m_b = mnew; l_b *= scl;
#pragma unroll
                for (int dn = 0; dn < 4; dn++)
#pragma unroll
                    for (int r = 0; r < 4; r++) acc_b[dn][r] *= scl;
            }
            float p[4][4];
#pragma unroll
            for (int n = 0; n < 4; n++)
#pragma unroll
                for (int r = 0; r < 4; r++) p[n][r] = __builtin_amdgcn_exp2f(sb[n][r] - m_b);
#pragma unroll
            for (int j = 0; j < 8; j++) {
                pb0[j] = (__bf16)p[j >> 2][j & 3];
                pb1[j] = (__bf16)p[2 + (j >> 2)][j & 3];
            }
        }

        // ---- PV + l-sum cluster ----
        f32x4 la = zero4, lb = zero4;
        __builtin_amdgcn_s_setprio(1);
#pragma unroll
        for (int ks = 0; ks < 2; ks++) {
            bf16x8 pA = ks ? pa1 : pa0;
            bf16x8 pB = ks ? pb1 : pb0;
#pragma unroll
            for (int dn = 0; dn < 4; dn++) {
                bf16x8 vf = *reinterpret_cast<const bf16x8*>(&Vf[cur][dn * 2 + ks][lane][0]);
                acc_a[dn] = __builtin_amdgcn_mfma_f32_16x16x32_bf16(vf, pA, acc_a[dn], 0, 0, 0);
                acc_b[dn] = __builtin_amdgcn_mfma_f32_16x16x32_bf16(vf, pB, acc_b[dn], 0, 0, 0);
            }
        }
        la = __builtin_amdgcn_mfma_f32_16x16x32_bf16(ones8, pa0, la, 0, 0, 0);
        la = __builtin_amdgcn_mfma_f32_16x16x32_bf16(ones8, pa1, la, 0, 0, 0);
        lb = __builtin_amdgcn_mfma_f32_16x16x32_bf16(ones8, pb0, lb, 0, 0, 0);
        lb = __builtin_amdgcn_mfma_f32_16x16x32_bf16(ones8, pb1, lb, 0, 0, 0);
        __builtin_amdgcn_s_setprio(0);
        l_a += la[0];
        l_b += lb[0];

        // ---- stage next tile into the other buffer; ONE barrier per tile ----
        if (kt + 1 < NT) stage_write(cur ^ 1);
        __syncthreads();
        cur ^= 1;
    }

    // normalize and write O: lane holds O[q = l15][d = dn*16 + g*4 + r]
    float inv_a = 1.0f / l_a;
    float inv_b = 1.0f / l_b;
    unsigned short* oA = Oa + (size_t)(b * SS + qA + l15) * HH + h * HDD;
    unsigned short* oB = oA + (size_t)16 * HH;
#pragma unroll
    for (int dn = 0; dn < 4; dn++) {
        ushort4 wa, wb;
        wa.x = f2b(acc_a[dn][0] * inv_a); wa.y = f2b(acc_a[dn][1] * inv_a);
        wa.z = f2b(acc_a[dn][2] * inv_a); wa.w = f2b(acc_a[dn][3] * inv_a);
        wb.x = f2b(acc_b[dn][0] * inv_b); wb.y = f2b(acc_b[dn][1] * inv_b);
        wb.z = f2b(acc_b[dn][2] * inv_b); wb.w = f2b(acc_b[dn][3] * inv_b);
        *reinterpret_cast<ushort4*>(oA + dn * 16 + g * 4) = wa;
        *reinterpret_cast<ushort4*>(oB + dn * 16 + g * 4) = wb;
    }
}

// ---------------- launcher ----------------
extern "C" void kernel_launch(void* const* d_in, const int* in_sizes, int n_in,
                              void* d_out, int out_size, void* d_ws, size_t ws_size,
                              hipStream_t stream) {
    const float* x  = (const float*)d_in[0];
    const float* Wq = (const float*)d_in[1];
    const float* bq = (const float*)d_in[2];
    const float* Wk = (const float*)d_in[3];
    const float* bk = (const float*)d_in[4];
    const float* Wv = (const float*)d_in[5];
    const float* bv = (const float*)d_in[6];
    const float* Wo = (const float*)d_in[7];
    const float* bo = (const float*)d_in[8];
    float* out = (float*)d_out;

    const int M = BB * SS;   // 8192
    const long nx = (long)M * HH;       // 8388608

    unsigned char* ws = (unsigned char*)d_ws;
    unsigned short* xb  = (unsigned short*)(ws);
    unsigned short* Wqb = (unsigned short*)(ws + 16777216);   // Wq,Wk,Wv,Wo contiguous
    unsigned short* Wob = (unsigned short*)(ws + 16777216 + 3 * 2097152);
    unsigned short* Qb  = (unsigned short*)(ws + 16777216 + 4 * 2097152);
    unsigned short* Kb  = (unsigned short*)(ws + 2 * 16777216 + 4 * 2097152);
    unsigned short* Vtb = (unsigned short*)(ws + 3 * 16777216 + 4 * 2097152);
    unsigned short* Ab  = (unsigned short*)(ws + 4 * 16777216 + 4 * 2097152);

    // fp32 -> bf16
    cvt_bf16<<<4096, 256, 0, stream>>>(x, xb, nx);
    cvt_w4<<<dim3(256, 4), 256, 0, stream>>>(Wq, Wk, Wv, Wo, Wqb);

    // fused QKV projection: N = 3072, 1536 wgs, XCD-chunked
    gemm_qkv<<<1536, 256, 0, stream>>>(xb, Wqb, bq, bk, bv, Qb, Kb, Vtb);

    // attention: 1024 wgs, XCD-chunked
    attn_kernel<<<1024, 256, 0, stream>>>(Qb, Kb, Vtb, Ab);

    // out-projection: 512 wgs, XCD-chunked
    gemm_out<<<512, 256, 0, stream>>>(Ab, Wob, bo, out, M, HH, HH);
}

// Round 7
// 233.984 us; speedup vs baseline: 1.0311x; 1.0311x over previous
//
#include <hip/hip_runtime.h>
#include <cstdint>

// Problem constants
#define BB 4
#define SS 2048
#define HH 1024
#define NHH 16
#define HDD 64
// M = BB*SS = 8192

typedef __bf16 bf16x8 __attribute__((ext_vector_type(8)));
typedef float f32x4 __attribute__((ext_vector_type(4)));
typedef unsigned short u16x8 __attribute__((ext_vector_type(8)));

__device__ __forceinline__ unsigned short f2b(float f) {
    unsigned int u = __float_as_uint(f);
    u += 0x7fffu + ((u >> 16) & 1u);   // round-to-nearest-even
    return (unsigned short)(u >> 16);
}

__device__ __forceinline__ void gload_lds16(const void* g, void* l) {
    __builtin_amdgcn_global_load_lds(
        (const __attribute__((address_space(1))) void*)g,
        (__attribute__((address_space(3))) void*)l, 16, 0, 0);
}

// ---------------- fp32 -> bf16 conversion ----------------
__global__ void cvt_bf16(const float* __restrict__ in,
                         unsigned short* __restrict__ out, long n) {
    long i = ((long)blockIdx.x * blockDim.x + threadIdx.x) * 4;
    long stride = (long)gridDim.x * blockDim.x * 4;
    for (; i < n; i += stride) {
        float4 v = *reinterpret_cast<const float4*>(in + i);
        ushort4 o;
        o.x = f2b(v.x); o.y = f2b(v.y); o.z = f2b(v.z); o.w = f2b(v.w);
        *reinterpret_cast<ushort4*>(out + i) = o;
    }
}

// 4 weight matrices (each HH*HH), outputs contiguous at out + y*HH*HH
__global__ void cvt_w4(const float* __restrict__ w0, const float* __restrict__ w1,
                       const float* __restrict__ w2, const float* __restrict__ w3,
                       unsigned short* __restrict__ out) {
    const float* s = blockIdx.y == 0 ? w0 : blockIdx.y == 1 ? w1 : blockIdx.y == 2 ? w2 : w3;
    unsigned short* o = out + (size_t)blockIdx.y * ((size_t)HH * HH);
    long n = (long)HH * HH;
    long stride = (long)gridDim.x * blockDim.x * 4;
    for (long i = ((long)blockIdx.x * blockDim.x + threadIdx.x) * 4; i < n; i += stride) {
        float4 v = *reinterpret_cast<const float4*>(s + i);
        ushort4 w;
        w.x = f2b(v.x); w.y = f2b(v.y); w.z = f2b(v.z); w.w = f2b(v.w);
        *reinterpret_cast<ushort4*>(o + i) = w;
    }
}

// ---------------- fused QKV GEMM (2-phase dbuf, XCD-chunked 16x12) ----------------
// A[8192][1024] bf16; Bqkv[3072][1024] bf16 (Wq,Wk,Wv stacked).
// 1536 wgs: XCD x = wg&7 owns rows [(x&3)*16..+16) x cols [(x>>2)*12..+12),
// cols fastest -> per-XCD B slice 3MB L2-resident, A 4MB streamed once.
__global__ __launch_bounds__(256) void gemm_qkv(
    const unsigned short* __restrict__ A,
    const unsigned short* __restrict__ Bqkv,
    const float* __restrict__ bq, const float* __restrict__ bk,
    const float* __restrict__ bv,
    unsigned short* __restrict__ Qo, unsigned short* __restrict__ Ko,
    unsigned short* __restrict__ Vto)
{
    __shared__ alignas(16) unsigned short Al[2][128][32];
    __shared__ alignas(16) unsigned short Bl[2][128][32];

    const int tid = threadIdx.x;
    const int lane = tid & 63;
    const int wid  = tid >> 6;
    const int wm = wid >> 1, wn = wid & 1;
    const int l15 = lane & 15, g = lane >> 4;

    const int wg = blockIdx.x;
    const int x = wg & 7;
    const int local = wg >> 3;                 // 0..191
    const int row0 = ((x & 3) * 16 + local / 12) * 128;
    const int col0 = ((x >> 2) * 12 + local % 12) * 128;
    const int nb = col0 >> 10;                 // 0:Q 1:K 2:V
    const int cbase = col0 & 1023;
    const float* bias = nb == 0 ? bq : nb == 1 ? bk : bv;
    const int K = HH;

    f32x4 acc[4][4];
#pragma unroll
    for (int i = 0; i < 4; i++)
#pragma unroll
        for (int j = 0; j < 4; j++) acc[i][j] = (f32x4)0.0f;

    // staging geometry (per thread): two 16B pieces of the 8KB tile
    const int off0 = tid * 16;
    const int aoff0 = (off0 >> 6) * (K * 2) + (off0 & 63);
    const int off1 = off0 + 4096;
    const int aoff1 = (off1 >> 6) * (K * 2) + (off1 & 63);

    const char* gAb = (const char*)(A + (size_t)row0 * K);
    const char* gBb = (const char*)(Bqkv + (size_t)col0 * K);

    auto STAGE = [&](int buf, int k0) {
        const char* a = gAb + k0 * 64;
        const char* bsrc = gBb + k0 * 64;
        char* lA = (char*)&Al[buf][0][0] + wid * 1024;
        char* lB = (char*)&Bl[buf][0][0] + wid * 1024;
        gload_lds16(a + aoff0, lA);
        gload_lds16(a + aoff1, lA + 4096);
        gload_lds16(bsrc + aoff0, lB);
        gload_lds16(bsrc + aoff1, lB + 4096);
    };

    STAGE(0, 0);
    __syncthreads();
    int cur = 0;

    for (int k = 0; k < 32; k++) {
        if (k + 1 < 32) STAGE(cur ^ 1, k + 1);   // loads fly across this tile's MFMA

        bf16x8 af[4], bf[4];
#pragma unroll
        for (int i = 0; i < 4; i++)
            af[i] = *reinterpret_cast<const bf16x8*>(&Al[cur][wm * 64 + i * 16 + l15][g * 8]);
#pragma unroll
        for (int j = 0; j < 4; j++)
            bf[j] = *reinterpret_cast<const bf16x8*>(&Bl[cur][wn * 64 + j * 16 + l15][g * 8]);
#pragma unroll
        for (int i = 0; i < 4; i++)
#pragma unroll
            for (int j = 0; j < 4; j++)
                acc[i][j] = __builtin_amdgcn_mfma_f32_16x16x32_bf16(af[i], bf[j], acc[i][j], 0, 0, 0);
        __syncthreads();       // drains vmcnt (next tile staged) + all reads of cur done
        cur ^= 1;
    }

#pragma unroll
    for (int i = 0; i < 4; i++) {
#pragma unroll
        for (int j = 0; j < 4; j++) {
#pragma unroll
            for (int r = 0; r < 4; r++) {
                int row = row0 + wm * 64 + i * 16 + g * 4 + r;
                int col = cbase + wn * 64 + j * 16 + l15;
                float v = acc[i][j][r] + bias[col];
                if (nb == 0) {
                    Qo[(size_t)row * HH + col] = f2b(v);
                } else if (nb == 1) {
                    Ko[(size_t)row * HH + col] = f2b(v);
                } else {
                    int b = row >> 11;
                    int s = row & (SS - 1);
                    int s6 = s & 63;
                    int sp6 = (s6 & 0x23) | ((s6 & 0x0C) << 1) | ((s6 & 0x10) >> 2);
                    int head = col >> 6;
                    int d = col & (HDD - 1);
                    size_t idx = (((size_t)b * NHH + head) * HDD + d) * SS + (s & ~63) + sp6;
                    Vto[idx] = f2b(v);
                }
            }
        }
    }
}

// ---------------- out-projection GEMM (fp32 out, 2-phase dbuf, XCD-chunked 8x8) ----------------
__global__ __launch_bounds__(256) void gemm_out(
    const unsigned short* __restrict__ A,   // [M][K] bf16
    const unsigned short* __restrict__ Bm,  // [N][K] bf16
    const float* __restrict__ bias,         // [N]
    float* __restrict__ Cout,
    int M, int N, int K)
{
    __shared__ alignas(16) unsigned short Al[2][128][32];
    __shared__ alignas(16) unsigned short Bl[2][128][32];

    const int tid = threadIdx.x;
    const int lane = tid & 63;
    const int wid  = tid >> 6;
    const int wm = wid >> 1, wn = wid & 1;
    const int l15 = lane & 15, g = lane >> 4;

    const int wg = blockIdx.x;
    const int x = wg & 7;
    const int local = wg >> 3;                 // 0..63
    const int row0 = (x * 8 + local / 8) * 128;
    const int col0 = (local % 8) * 128;

    f32x4 acc[4][4];
#pragma unroll
    for (int i = 0; i < 4; i++)
#pragma unroll
        for (int j = 0; j < 4; j++) acc[i][j] = (f32x4)0.0f;

    const int off0 = tid * 16;
    const int aoff0 = (off0 >> 6) * (K * 2) + (off0 & 63);
    const int off1 = off0 + 4096;
    const int aoff1 = (off1 >> 6) * (K * 2) + (off1 & 63);

    const char* gAb = (const char*)(A + (size_t)row0 * K);
    const char* gBb = (const char*)(Bm + (size_t)col0 * K);

    auto STAGE = [&](int buf, int k0) {
        const char* a = gAb + k0 * 64;
        const char* bsrc = gBb + k0 * 64;
        char* lA = (char*)&Al[buf][0][0] + wid * 1024;
        char* lB = (char*)&Bl[buf][0][0] + wid * 1024;
        gload_lds16(a + aoff0, lA);
        gload_lds16(a + aoff1, lA + 4096);
        gload_lds16(bsrc + aoff0, lB);
        gload_lds16(bsrc + aoff1, lB + 4096);
    };

    STAGE(0, 0);
    __syncthreads();
    int cur = 0;

    for (int k = 0; k < 32; k++) {
        if (k + 1 < 32) STAGE(cur ^ 1, k + 1);

        bf16x8 af[4], bf[4];
#pragma unroll
        for (int i = 0; i < 4; i++)
            af[i] = *reinterpret_cast<const bf16x8*>(&Al[cur][wm * 64 + i * 16 + l15][g * 8]);
#pragma unroll
        for (int j = 0; j < 4; j++)
            bf[j] = *reinterpret_cast<const bf16x8*>(&Bl[cur][wn * 64 + j * 16 + l15][g * 8]);
#pragma unroll
        for (int i = 0; i < 4; i++)
#pragma unroll
            for (int j = 0; j < 4; j++)
                acc[i][j] = __builtin_amdgcn_mfma_f32_16x16x32_bf16(af[i], bf[j], acc[i][j], 0, 0, 0);
        __syncthreads();
        cur ^= 1;
    }

#pragma unroll
    for (int i = 0; i < 4; i++) {
#pragma unroll
        for (int j = 0; j < 4; j++) {
#pragma unroll
            for (int r = 0; r < 4; r++) {
                int row = row0 + wm * 64 + i * 16 + g * 4 + r;
                int col = col0 + wn * 64 + j * 16 + l15;
                Cout[(size_t)row * N + col] = acc[i][j][r] + bias[col];
            }
        }
    }
}

// ---------------- Flash attention (swapped QK^T, fragment-linear LDS) ----------------
// Q,K: bf16 [B*S][H];  Vt: bf16 [B][NH][HD][S] key-permuted;  Oa: bf16 [B*S][H]
// 1024 workgroups, XCD-chunked: each XCD owns 8 (b,h) pairs x 16 q-tiles
// contiguous -> that head's K/V (512KB) stays L2-resident.
__global__ __launch_bounds__(256, 4) void attn_kernel(
    const unsigned short* __restrict__ Q,
    const unsigned short* __restrict__ K,
    const unsigned short* __restrict__ Vt,
    unsigned short* __restrict__ Oa)
{
    __shared__ alignas(16) unsigned short Kf[2][8][64][8];
    __shared__ alignas(16) unsigned short Vf[2][8][64][8];

    const int tid = threadIdx.x;
    const int lane = tid & 63;
    const int wid  = tid >> 6;
    const int l15 = lane & 15, g = lane >> 4;

    // bijective XCD chunk swizzle: nwg=1024, chunk=128; q-tile fastest
    const int wg = blockIdx.x;
    const int L = (wg & 7) * 128 + (wg >> 3);
    const int qt = L & 15;
    const int bh = L >> 4;
    const int b  = bh >> 4;
    const int h  = bh & 15;
    const int q0 = qt * 128;
    const int qA = q0 + wid * 32;       // wave handles q-cols qA..+15 (A), qA+16..+31 (B)

    // Q as B-fragments, prescaled into log2 domain
    const float qs = 0.125f * 1.44269504088896f;
    const unsigned short* qpA = Q + (size_t)(b * SS + qA + l15) * HH + h * HDD + g * 8;
    const unsigned short* qpB = qpA + (size_t)16 * HH;
    u16x8 ra0 = *reinterpret_cast<const u16x8*>(qpA);
    u16x8 ra1 = *reinterpret_cast<const u16x8*>(qpA + 32);
    u16x8 rb0 = *reinterpret_cast<const u16x8*>(qpB);
    u16x8 rb1 = *reinterpret_cast<const u16x8*>(qpB + 32);
#pragma unroll
    for (int j = 0; j < 8; j++) {
        ra0[j] = f2b(__uint_as_float((unsigned)ra0[j] << 16) * qs);
        ra1[j] = f2b(__uint_as_float((unsigned)ra1[j] << 16) * qs);
        rb0[j] = f2b(__uint_as_float((unsigned)rb0[j] << 16) * qs);
        rb1[j] = f2b(__uint_as_float((unsigned)rb1[j] << 16) * qs);
    }
    const bf16x8 qa0 = __builtin_bit_cast(bf16x8, ra0);
    const bf16x8 qa1 = __builtin_bit_cast(bf16x8, ra1);
    const bf16x8 qb0 = __builtin_bit_cast(bf16x8, rb0);
    const bf16x8 qb1 = __builtin_bit_cast(bf16x8, rb1);

    u16x8 ou;
#pragma unroll
    for (int j = 0; j < 8; j++) ou[j] = 0x3F80;   // bf16 1.0
    const bf16x8 ones8 = __builtin_bit_cast(bf16x8, ou);
    const f32x4 zero4 = (f32x4)0.0f;

    f32x4 acc_a[4], acc_b[4];
#pragma unroll
    for (int dn = 0; dn < 4; dn++) { acc_a[dn] = zero4; acc_b[dn] = zero4; }
    float m_a = -INFINITY, m_b = -INFINITY, l_a = 0.f, l_b = 0.f;

    // staging geometry: thread holds row srow, 8-short units d0a and d0a+1
    const int srow = tid >> 2;            // 0..63 (K: key row; V: d row)
    const int d0a  = (tid & 3) * 2;       // unit index 0,2,4,6
    const int sfrag = ((srow >> 4) << 1) + (d0a >> 2);
    const int sslot = (srow & 15) | ((d0a & 3) << 4);

    const unsigned short* gK = K  + (size_t)(b * SS + srow) * HH + h * HDD + d0a * 8;
    const unsigned short* gV = Vt + (((size_t)b * NHH + h) * HDD + srow) * SS + d0a * 8;

    int4 kr0, kr1, vr0, vr1;

    auto stage_write = [&](int buf) {
        unsigned short* pk = &Kf[buf][sfrag][0][0] + sslot * 8;
        unsigned short* pv = &Vf[buf][sfrag][0][0] + sslot * 8;
        *reinterpret_cast<int4*>(pk)       = kr0;
        *reinterpret_cast<int4*>(pk + 128) = kr1;   // slot+16
        *reinterpret_cast<int4*>(pv)       = vr0;
        *reinterpret_cast<int4*>(pv + 128) = vr1;
    };

    // prologue: tile 0
    kr0 = *reinterpret_cast<const int4*>(gK);
    kr1 = *reinterpret_cast<const int4*>(gK + 8);
    vr0 = *reinterpret_cast<const int4*>(gV);
    vr1 = *reinterpret_cast<const int4*>(gV + 8);
    stage_write(0);
    gK += (size_t)64 * HH;
    gV += 64;
    __syncthreads();

    const int NT = SS / 64;
    int cur = 0;

    for (int kt = 0; kt < NT; kt++) {
        if (kt + 1 < NT) {   // issue next tile's loads; land in regs across compute
            kr0 = *reinterpret_cast<const int4*>(gK);
            kr1 = *reinterpret_cast<const int4*>(gK + 8);
            vr0 = *reinterpret_cast<const int4*>(gV);
            vr1 = *reinterpret_cast<const int4*>(gV + 8);
            gK += (size_t)64 * HH;
            gV += 64;
        }

        // ---- QK^T cluster: C[key][q], K-frags read once, shared by A and B ----
        f32x4 sa[4], sb[4];
        __builtin_amdgcn_s_setprio(1);
#pragma unroll
        for (int n = 0; n < 4; n++) {
            bf16x8 kf0 = *reinterpret_cast<const bf16x8*>(&Kf[cur][n * 2 + 0][lane][0]);
            bf16x8 kf1 = *reinterpret_cast<const bf16x8*>(&Kf[cur][n * 2 + 1][lane][0]);
            sa[n] = __builtin_amdgcn_mfma_f32_16x16x32_bf16(kf0, qa0, zero4, 0, 0, 0);
            sa[n] = __builtin_amdgcn_mfma_f32_16x16x32_bf16(kf1, qa1, sa[n], 0, 0, 0);
            sb[n] = __builtin_amdgcn_mfma_f32_16x16x32_bf16(kf0, qb0, zero4, 0, 0, 0);
            sb[n] = __builtin_amdgcn_mfma_f32_16x16x32_bf16(kf1, qb1, sb[n], 0, 0, 0);
        }
        __builtin_amdgcn_s_setprio(0);

        // ---- softmax A (sa dies into pa), then softmax B ----
        bf16x8 pa0, pa1, pb0, pb1;
        {
            float u0 = fmaxf(fmaxf(sa[0][0], sa[0][1]), fmaxf(sa[0][2], sa[0][3]));
            float u1 = fmaxf(fmaxf(sa[1][0], sa[1][1]), fmaxf(sa[1][2], sa[1][3]));
            float u2 = fmaxf(fmaxf(sa[2][0], sa[2][1]), fmaxf(sa[2][2], sa[2][3]));
            float u3 = fmaxf(fmaxf(sa[3][0], sa[3][1]), fmaxf(sa[3][2], sa[3][3]));
            float mt = fmaxf(fmaxf(u0, u1), fmaxf(u2, u3));
            mt = fmaxf(mt, __shfl_xor(mt, 16));
            mt = fmaxf(mt, __shfl_xor(mt, 32));
            if (!__all(mt - m_a <= 8.0f)) {
                float mnew = fmaxf(m_a, mt);
                float scl = __builtin_amdgcn_exp2f(m_a - mnew);
                m_a = mnew; l_a *= scl;
#pragma unroll
                for (int dn = 0; dn < 4; dn++)
#pragma unroll
                    for (int r = 0; r < 4; r++) acc_a[dn][r] *= scl;
            }
            float p[4][4];
#pragma unroll
            for (int n = 0; n < 4; n++)
#pragma unroll
                for (int r = 0; r < 4; r++) p[n][r] = __builtin_amdgcn_exp2f(sa[n][r] - m_a);
#pragma unroll
            for (int j = 0; j < 8; j++) {
                pa0[j] = (__bf16)p[j >> 2][j & 3];
                pa1[j] = (__bf16)p[2 + (j >> 2)][j & 3];
            }
        }
        {
            float u0 = fmaxf(fmaxf(sb[0][0], sb[0][1]), fmaxf(sb[0][2], sb[0][3]));
            float u1 = fmaxf(fmaxf(sb[1][0], sb[1][1]), fmaxf(sb[1][2], sb[1][3]));
            float u2 = fmaxf(fmaxf(sb[2][0], sb[2][1]), fmaxf(sb[2][2], sb[2][3]));
            float u3 = fmaxf(fmaxf(sb[3][0], sb[3][1]), fmaxf(sb[3][2], sb[3][3]));
            float mt = fmaxf(fmaxf(u0, u1), fmaxf(u2, u3));
            mt = fmaxf(mt, __shfl_xor(mt, 16));
            mt = fmaxf(mt, __shfl_xor(mt, 32));
            if (!__all(mt - m_b <= 8.0f)) {
                float mnew = fmaxf(m_b, mt);
                float scl = __builtin_amdgcn_exp2f(m_b - mnew);
                m_b = mnew; l_b *= scl;
#pragma unroll
                for (int dn = 0; dn < 4; dn++)
#pragma unroll
                    for (int r = 0; r < 4; r++) acc_b[dn][r] *= scl;
            }
            float p[4][4];
#pragma unroll
            for (int n = 0; n < 4; n++)
#pragma unroll
                for (int r = 0; r < 4; r++) p[n][r] = __builtin_amdgcn_exp2f(sb[n][r] - m_b);
#pragma unroll
            for (int j = 0; j < 8; j++) {
                pb0[j] = (__bf16)p[j >> 2][j & 3];
                pb1[j] = (__bf16)p[2 + (j >> 2)][j & 3];
            }
        }

        // ---- PV + l-sum cluster ----
        f32x4 la = zero4, lb = zero4;
        __builtin_amdgcn_s_setprio(1);
#pragma unroll
        for (int ks = 0; ks < 2; ks++) {
            bf16x8 pA = ks ? pa1 : pa0;
            bf16x8 pB = ks ? pb1 : pb0;
#pragma unroll
            for (int dn = 0; dn < 4; dn++) {
                bf16x8 vf = *reinterpret_cast<const bf16x8*>(&Vf[cur][dn * 2 + ks][lane][0]);
                acc_a[dn] = __builtin_amdgcn_mfma_f32_16x16x32_bf16(vf, pA, acc_a[dn], 0, 0, 0);
                acc_b[dn] = __builtin_amdgcn_mfma_f32_16x16x32_bf16(vf, pB, acc_b[dn], 0, 0, 0);
            }
        }
        la = __builtin_amdgcn_mfma_f32_16x16x32_bf16(ones8, pa0, la, 0, 0, 0);
        la = __builtin_amdgcn_mfma_f32_16x16x32_bf16(ones8, pa1, la, 0, 0, 0);
        lb = __builtin_amdgcn_mfma_f32_16x16x32_bf16(ones8, pb0, lb, 0, 0, 0);
        lb = __builtin_amdgcn_mfma_f32_16x16x32_bf16(ones8, pb1, lb, 0, 0, 0);
        __builtin_amdgcn_s_setprio(0);
        l_a += la[0];
        l_b += lb[0];

        // ---- stage next tile into the other buffer; ONE barrier per tile ----
        if (kt + 1 < NT) stage_write(cur ^ 1);
        __syncthreads();
        cur ^= 1;
    }

    // normalize and write O: lane holds O[q = l15][d = dn*16 + g*4 + r]
    float inv_a = 1.0f / l_a;
    float inv_b = 1.0f / l_b;
    unsigned short* oA = Oa + (size_t)(b * SS + qA + l15) * HH + h * HDD;
    unsigned short* oB = oA + (size_t)16 * HH;
#pragma unroll
    for (int dn = 0; dn < 4; dn++) {
        ushort4 wa, wb;
        wa.x = f2b(acc_a[dn][0] * inv_a); wa.y = f2b(acc_a[dn][1] * inv_a);
        wa.z = f2b(acc_a[dn][2] * inv_a); wa.w = f2b(acc_a[dn][3] * inv_a);
        wb.x = f2b(acc_b[dn][0] * inv_b); wb.y = f2b(acc_b[dn][1] * inv_b);
        wb.z = f2b(acc_b[dn][2] * inv_b); wb.w = f2b(acc_b[dn][3] * inv_b);
        *reinterpret_cast<ushort4*>(oA + dn * 16 + g * 4) = wa;
        *reinterpret_cast<ushort4*>(oB + dn * 16 + g * 4) = wb;
    }
}

// ---------------- launcher ----------------
extern "C" void kernel_launch(void* const* d_in, const int* in_sizes, int n_in,
                              void* d_out, int out_size, void* d_ws, size_t ws_size,
                              hipStream_t stream) {
    const float* x  = (const float*)d_in[0];
    const float* Wq = (const float*)d_in[1];
    const float* bq = (const float*)d_in[2];
    const float* Wk = (const float*)d_in[3];
    const float* bk = (const float*)d_in[4];
    const float* Wv = (const float*)d_in[5];
    const float* bv = (const float*)d_in[6];
    const float* Wo = (const float*)d_in[7];
    const float* bo = (const float*)d_in[8];
    float* out = (float*)d_out;

    const int M = BB * SS;   // 8192
    const long nx = (long)M * HH;       // 8388608

    unsigned char* ws = (unsigned char*)d_ws;
    unsigned short* xb  = (unsigned short*)(ws);
    unsigned short* Wqb = (unsigned short*)(ws + 16777216);   // Wq,Wk,Wv,Wo contiguous
    unsigned short* Wob = (unsigned short*)(ws + 16777216 + 3 * 2097152);
    unsigned short* Qb  = (unsigned short*)(ws + 16777216 + 4 * 2097152);
    unsigned short* Kb  = (unsigned short*)(ws + 2 * 16777216 + 4 * 2097152);
    unsigned short* Vtb = (unsigned short*)(ws + 3 * 16777216 + 4 * 2097152);
    unsigned short* Ab  = (unsigned short*)(ws + 4 * 16777216 + 4 * 2097152);

    // fp32 -> bf16
    cvt_bf16<<<4096, 256, 0, stream>>>(x, xb, nx);
    cvt_w4<<<dim3(256, 4), 256, 0, stream>>>(Wq, Wk, Wv, Wo, Wqb);

    // fused QKV projection: N = 3072, 1536 wgs, XCD-chunked 16x12 cols-fastest
    gemm_qkv<<<1536, 256, 0, stream>>>(xb, Wqb, bq, bk, bv, Qb, Kb, Vtb);

    // attention: 1024 wgs, XCD-chunked
    attn_kernel<<<1024, 256, 0, stream>>>(Qb, Kb, Vtb, Ab);

    // out-projection: 512 wgs, XCD-chunked 8x8 cols-fastest
    gemm_out<<<512, 256, 0, stream>>>(Ab, Wob, bo, out, M, HH, HH);
}

// Round 8
// 222.703 us; speedup vs baseline: 1.0834x; 1.0507x over previous
//
#include <hip/hip_runtime.h>
#include <cstdint>

// Problem constants
#define BB 4
#define SS 2048
#define HH 1024
#define NHH 16
#define HDD 64
// M = BB*SS = 8192

typedef __bf16 bf16x8 __attribute__((ext_vector_type(8)));
typedef float f32x4 __attribute__((ext_vector_type(4)));
typedef unsigned short u16x8 __attribute__((ext_vector_type(8)));

__device__ __forceinline__ unsigned short f2b(float f) {
    unsigned int u = __float_as_uint(f);
    u += 0x7fffu + ((u >> 16) & 1u);   // round-to-nearest-even
    return (unsigned short)(u >> 16);
}

__device__ __forceinline__ void gload_lds16(const void* g, void* l) {
    __builtin_amdgcn_global_load_lds(
        (const __attribute__((address_space(1))) void*)g,
        (__attribute__((address_space(3))) void*)l, 16, 0, 0);
}

// ---------------- fp32 -> bf16 conversion ----------------
__global__ void cvt_bf16(const float* __restrict__ in,
                         unsigned short* __restrict__ out, long n) {
    long i = ((long)blockIdx.x * blockDim.x + threadIdx.x) * 4;
    long stride = (long)gridDim.x * blockDim.x * 4;
    for (; i < n; i += stride) {
        float4 v = *reinterpret_cast<const float4*>(in + i);
        ushort4 o;
        o.x = f2b(v.x); o.y = f2b(v.y); o.z = f2b(v.z); o.w = f2b(v.w);
        *reinterpret_cast<ushort4*>(out + i) = o;
    }
}

// 4 weight matrices (each HH*HH), outputs contiguous at out + y*HH*HH
__global__ void cvt_w4(const float* __restrict__ w0, const float* __restrict__ w1,
                       const float* __restrict__ w2, const float* __restrict__ w3,
                       unsigned short* __restrict__ out) {
    const float* s = blockIdx.y == 0 ? w0 : blockIdx.y == 1 ? w1 : blockIdx.y == 2 ? w2 : w3;
    unsigned short* o = out + (size_t)blockIdx.y * ((size_t)HH * HH);
    long n = (long)HH * HH;
    long stride = (long)gridDim.x * blockDim.x * 4;
    for (long i = ((long)blockIdx.x * blockDim.x + threadIdx.x) * 4; i < n; i += stride) {
        float4 v = *reinterpret_cast<const float4*>(s + i);
        ushort4 w;
        w.x = f2b(v.x); w.y = f2b(v.y); w.z = f2b(v.z); w.w = f2b(v.w);
        *reinterpret_cast<ushort4*>(o + i) = w;
    }
}

// ---------------- fused QKV GEMM (3-buf depth-2 counted-vmcnt pipeline) ----------------
// A[8192][1024] bf16; Bqkv[3072][1024] bf16 (Wq,Wk,Wv stacked).
// 1536 wgs: XCD x = wg&7 owns rows [(x&3)*16..+16) x cols [(x>>2)*12..+12).
__global__ __launch_bounds__(256) void gemm_qkv(
    const unsigned short* __restrict__ A,
    const unsigned short* __restrict__ Bqkv,
    const float* __restrict__ bq, const float* __restrict__ bk,
    const float* __restrict__ bv,
    unsigned short* __restrict__ Qo, unsigned short* __restrict__ Ko,
    unsigned short* __restrict__ Vto)
{
    __shared__ alignas(16) unsigned short Al[3][128][32];
    __shared__ alignas(16) unsigned short Bl[3][128][32];

    const int tid = threadIdx.x;
    const int lane = tid & 63;
    const int wid  = tid >> 6;
    const int wm = wid >> 1, wn = wid & 1;
    const int l15 = lane & 15, g = lane >> 4;

    const int wg = blockIdx.x;
    const int x = wg & 7;
    const int local = wg >> 3;                 // 0..191
    const int row0 = ((x & 3) * 16 + local / 12) * 128;
    const int col0 = ((x >> 2) * 12 + local % 12) * 128;
    const int nb = col0 >> 10;                 // 0:Q 1:K 2:V
    const int cbase = col0 & 1023;
    const float* bias = nb == 0 ? bq : nb == 1 ? bk : bv;
    const int K = HH;

    f32x4 acc[4][4];
#pragma unroll
    for (int i = 0; i < 4; i++)
#pragma unroll
        for (int j = 0; j < 4; j++) acc[i][j] = (f32x4)0.0f;

    // staging geometry (per thread): two 16B pieces of the 8KB tile
    const int off0 = tid * 16;
    const int aoff0 = (off0 >> 6) * (K * 2) + (off0 & 63);
    const int off1 = off0 + 4096;
    const int aoff1 = (off1 >> 6) * (K * 2) + (off1 & 63);

    const char* gAb = (const char*)(A + (size_t)row0 * K);
    const char* gBb = (const char*)(Bqkv + (size_t)col0 * K);

    char* A0 = (char*)&Al[0][0][0]; char* A1 = A0 + 8192; char* A2 = A0 + 16384;
    char* B0 = (char*)&Bl[0][0][0]; char* B1 = B0 + 8192; char* B2 = B0 + 16384;

    auto STAGE = [&](char* lA, char* lB, int k0) {
        const char* a = gAb + k0 * 64;
        const char* bsrc = gBb + k0 * 64;
        gload_lds16(a + aoff0, lA + wid * 1024);
        gload_lds16(a + aoff1, lA + wid * 1024 + 4096);
        gload_lds16(bsrc + aoff0, lB + wid * 1024);
        gload_lds16(bsrc + aoff1, lB + wid * 1024 + 4096);
    };

    // prologue: two tiles in flight
    STAGE(A0, B0, 0);
    STAGE(A1, B1, 1);

    for (int k = 0; k < 32; k++) {
        if (k < 30) STAGE(A2, B2, k + 2);   // stays in flight across 2 compute phases

        // counted wait: tile k landed, tiles k+1/k+2 still flying
        if (k < 30)       asm volatile("s_waitcnt vmcnt(8)" ::: "memory");
        else if (k == 30) asm volatile("s_waitcnt vmcnt(4)" ::: "memory");
        else              asm volatile("s_waitcnt vmcnt(0)" ::: "memory");
        __builtin_amdgcn_s_barrier();       // all waves' tile-k portions visible

        bf16x8 af[4], bf[4];
#pragma unroll
        for (int i = 0; i < 4; i++)
            af[i] = *reinterpret_cast<const bf16x8*>(A0 + ((wm * 64 + i * 16 + l15) * 32 + g * 8) * 2);
#pragma unroll
        for (int j = 0; j < 4; j++)
            bf[j] = *reinterpret_cast<const bf16x8*>(B0 + ((wn * 64 + j * 16 + l15) * 32 + g * 8) * 2);
#pragma unroll
        for (int i = 0; i < 4; i++)
#pragma unroll
            for (int j = 0; j < 4; j++)
                acc[i][j] = __builtin_amdgcn_mfma_f32_16x16x32_bf16(af[i], bf[j], acc[i][j], 0, 0, 0);

        __builtin_amdgcn_s_barrier();       // reads of buf k done before its rewrite next iter

        char* t = A0; A0 = A1; A1 = A2; A2 = t;   // rotate buffers
        t = B0; B0 = B1; B1 = B2; B2 = t;
    }

#pragma unroll
    for (int i = 0; i < 4; i++) {
#pragma unroll
        for (int j = 0; j < 4; j++) {
#pragma unroll
            for (int r = 0; r < 4; r++) {
                int row = row0 + wm * 64 + i * 16 + g * 4 + r;
                int col = cbase + wn * 64 + j * 16 + l15;
                float v = acc[i][j][r] + bias[col];
                if (nb == 0) {
                    Qo[(size_t)row * HH + col] = f2b(v);
                } else if (nb == 1) {
                    Ko[(size_t)row * HH + col] = f2b(v);
                } else {
                    int b = row >> 11;
                    int s = row & (SS - 1);
                    int s6 = s & 63;
                    int sp6 = (s6 & 0x23) | ((s6 & 0x0C) << 1) | ((s6 & 0x10) >> 2);
                    int head = col >> 6;
                    int d = col & (HDD - 1);
                    size_t idx = (((size_t)b * NHH + head) * HDD + d) * SS + (s & ~63) + sp6;
                    Vto[idx] = f2b(v);
                }
            }
        }
    }
}

// ---------------- out-projection GEMM (fp32 out, 3-buf counted-vmcnt, XCD 8x8) ----------------
__global__ __launch_bounds__(256) void gemm_out(
    const unsigned short* __restrict__ A,   // [M][K] bf16
    const unsigned short* __restrict__ Bm,  // [N][K] bf16
    const float* __restrict__ bias,         // [N]
    float* __restrict__ Cout,
    int M, int N, int K)
{
    __shared__ alignas(16) unsigned short Al[3][128][32];
    __shared__ alignas(16) unsigned short Bl[3][128][32];

    const int tid = threadIdx.x;
    const int lane = tid & 63;
    const int wid  = tid >> 6;
    const int wm = wid >> 1, wn = wid & 1;
    const int l15 = lane & 15, g = lane >> 4;

    const int wg = blockIdx.x;
    const int x = wg & 7;
    const int local = wg >> 3;                 // 0..63
    const int row0 = (x * 8 + local / 8) * 128;
    const int col0 = (local % 8) * 128;

    f32x4 acc[4][4];
#pragma unroll
    for (int i = 0; i < 4; i++)
#pragma unroll
        for (int j = 0; j < 4; j++) acc[i][j] = (f32x4)0.0f;

    const int off0 = tid * 16;
    const int aoff0 = (off0 >> 6) * (K * 2) + (off0 & 63);
    const int off1 = off0 + 4096;
    const int aoff1 = (off1 >> 6) * (K * 2) + (off1 & 63);

    const char* gAb = (const char*)(A + (size_t)row0 * K);
    const char* gBb = (const char*)(Bm + (size_t)col0 * K);

    char* A0 = (char*)&Al[0][0][0]; char* A1 = A0 + 8192; char* A2 = A0 + 16384;
    char* B0 = (char*)&Bl[0][0][0]; char* B1 = B0 + 8192; char* B2 = B0 + 16384;

    auto STAGE = [&](char* lA, char* lB, int k0) {
        const char* a = gAb + k0 * 64;
        const char* bsrc = gBb + k0 * 64;
        gload_lds16(a + aoff0, lA + wid * 1024);
        gload_lds16(a + aoff1, lA + wid * 1024 + 4096);
        gload_lds16(bsrc + aoff0, lB + wid * 1024);
        gload_lds16(bsrc + aoff1, lB + wid * 1024 + 4096);
    };

    STAGE(A0, B0, 0);
    STAGE(A1, B1, 1);

    for (int k = 0; k < 32; k++) {
        if (k < 30) STAGE(A2, B2, k + 2);

        if (k < 30)       asm volatile("s_waitcnt vmcnt(8)" ::: "memory");
        else if (k == 30) asm volatile("s_waitcnt vmcnt(4)" ::: "memory");
        else              asm volatile("s_waitcnt vmcnt(0)" ::: "memory");
        __builtin_amdgcn_s_barrier();

        bf16x8 af[4], bf[4];
#pragma unroll
        for (int i = 0; i < 4; i++)
            af[i] = *reinterpret_cast<const bf16x8*>(A0 + ((wm * 64 + i * 16 + l15) * 32 + g * 8) * 2);
#pragma unroll
        for (int j = 0; j < 4; j++)
            bf[j] = *reinterpret_cast<const bf16x8*>(B0 + ((wn * 64 + j * 16 + l15) * 32 + g * 8) * 2);
#pragma unroll
        for (int i = 0; i < 4; i++)
#pragma unroll
            for (int j = 0; j < 4; j++)
                acc[i][j] = __builtin_amdgcn_mfma_f32_16x16x32_bf16(af[i], bf[j], acc[i][j], 0, 0, 0);

        __builtin_amdgcn_s_barrier();

        char* t = A0; A0 = A1; A1 = A2; A2 = t;
        t = B0; B0 = B1; B1 = B2; B2 = t;
    }

#pragma unroll
    for (int i = 0; i < 4; i++) {
#pragma unroll
        for (int j = 0; j < 4; j++) {
#pragma unroll
            for (int r = 0; r < 4; r++) {
                int row = row0 + wm * 64 + i * 16 + g * 4 + r;
                int col = col0 + wn * 64 + j * 16 + l15;
                Cout[(size_t)row * N + col] = acc[i][j][r] + bias[col];
            }
        }
    }
}

// ---------------- Flash attention (swapped QK^T, fragment-linear LDS) ----------------
// Q,K: bf16 [B*S][H];  Vt: bf16 [B][NH][HD][S] key-permuted;  Oa: bf16 [B*S][H]
__global__ __launch_bounds__(256, 4) void attn_kernel(
    const unsigned short* __restrict__ Q,
    const unsigned short* __restrict__ K,
    const unsigned short* __restrict__ Vt,
    unsigned short* __restrict__ Oa)
{
    __shared__ alignas(16) unsigned short Kf[2][8][64][8];
    __shared__ alignas(16) unsigned short Vf[2][8][64][8];

    const int tid = threadIdx.x;
    const int lane = tid & 63;
    const int wid  = tid >> 6;
    const int l15 = lane & 15, g = lane >> 4;

    // bijective XCD chunk swizzle: nwg=1024, chunk=128; q-tile fastest
    const int wg = blockIdx.x;
    const int L = (wg & 7) * 128 + (wg >> 3);
    const int qt = L & 15;
    const int bh = L >> 4;
    const int b  = bh >> 4;
    const int h  = bh & 15;
    const int q0 = qt * 128;
    const int qA = q0 + wid * 32;       // wave handles q-cols qA..+15 (A), qA+16..+31 (B)

    // Q as B-fragments, prescaled into log2 domain
    const float qs = 0.125f * 1.44269504088896f;
    const unsigned short* qpA = Q + (size_t)(b * SS + qA + l15) * HH + h * HDD + g * 8;
    const unsigned short* qpB = qpA + (size_t)16 * HH;
    u16x8 ra0 = *reinterpret_cast<const u16x8*>(qpA);
    u16x8 ra1 = *reinterpret_cast<const u16x8*>(qpA + 32);
    u16x8 rb0 = *reinterpret_cast<const u16x8*>(qpB);
    u16x8 rb1 = *reinterpret_cast<const u16x8*>(qpB + 32);
#pragma unroll
    for (int j = 0; j < 8; j++) {
        ra0[j] = f2b(__uint_as_float((unsigned)ra0[j] << 16) * qs);
        ra1[j] = f2b(__uint_as_float((unsigned)ra1[j] << 16) * qs);
        rb0[j] = f2b(__uint_as_float((unsigned)rb0[j] << 16) * qs);
        rb1[j] = f2b(__uint_as_float((unsigned)rb1[j] << 16) * qs);
    }
    const bf16x8 qa0 = __builtin_bit_cast(bf16x8, ra0);
    const bf16x8 qa1 = __builtin_bit_cast(bf16x8, ra1);
    const bf16x8 qb0 = __builtin_bit_cast(bf16x8, rb0);
    const bf16x8 qb1 = __builtin_bit_cast(bf16x8, rb1);

    u16x8 ou;
#pragma unroll
    for (int j = 0; j < 8; j++) ou[j] = 0x3F80;   // bf16 1.0
    const bf16x8 ones8 = __builtin_bit_cast(bf16x8, ou);
    const f32x4 zero4 = (f32x4)0.0f;

    f32x4 acc_a[4], acc_b[4];
#pragma unroll
    for (int dn = 0; dn < 4; dn++) { acc_a[dn] = zero4; acc_b[dn] = zero4; }
    float m_a = -INFINITY, m_b = -INFINITY, l_a = 0.f, l_b = 0.f;

    // staging geometry: thread holds row srow, 8-short units d0a and d0a+1
    const int srow = tid >> 2;            // 0..63 (K: key row; V: d row)
    const int d0a  = (tid & 3) * 2;       // unit index 0,2,4,6
    const int sfrag = ((srow >> 4) << 1) + (d0a >> 2);
    const int sslot = (srow & 15) | ((d0a & 3) << 4);

    const unsigned short* gK = K  + (size_t)(b * SS + srow) * HH + h * HDD + d0a * 8;
    const unsigned short* gV = Vt + (((size_t)b * NHH + h) * HDD + srow) * SS + d0a * 8;

    int4 kr0, kr1, vr0, vr1;

    auto stage_write = [&](int buf) {
        unsigned short* pk = &Kf[buf][sfrag][0][0] + sslot * 8;
        unsigned short* pv = &Vf[buf][sfrag][0][0] + sslot * 8;
        *reinterpret_cast<int4*>(pk)       = kr0;
        *reinterpret_cast<int4*>(pk + 128) = kr1;   // slot+16
        *reinterpret_cast<int4*>(pv)       = vr0;
        *reinterpret_cast<int4*>(pv + 128) = vr1;
    };

    // prologue: tile 0
    kr0 = *reinterpret_cast<const int4*>(gK);
    kr1 = *reinterpret_cast<const int4*>(gK + 8);
    vr0 = *reinterpret_cast<const int4*>(gV);
    vr1 = *reinterpret_cast<const int4*>(gV + 8);
    stage_write(0);
    gK += (size_t)64 * HH;
    gV += 64;
    __syncthreads();

    const int NT = SS / 64;
    int cur = 0;

    for (int kt = 0; kt < NT; kt++) {
        if (kt + 1 < NT) {   // issue next tile's loads; land in regs across compute
            kr0 = *reinterpret_cast<const int4*>(gK);
            kr1 = *reinterpret_cast<const int4*>(gK + 8);
            vr0 = *reinterpret_cast<const int4*>(gV);
            vr1 = *reinterpret_cast<const int4*>(gV + 8);
            gK += (size_t)64 * HH;
            gV += 64;
        }

        // ---- QK^T cluster: C[key][q], K-frags read once, shared by A and B ----
        f32x4 sa[4], sb[4];
        __builtin_amdgcn_s_setprio(1);
#pragma unroll
        for (int n = 0; n < 4; n++) {
            bf16x8 kf0 = *reinterpret_cast<const bf16x8*>(&Kf[cur][n * 2 + 0][lane][0]);
            bf16x8 kf1 = *reinterpret_cast<const bf16x8*>(&Kf[cur][n * 2 + 1][lane][0]);
            sa[n] = __builtin_amdgcn_mfma_f32_16x16x32_bf16(kf0, qa0, zero4, 0, 0, 0);
            sa[n] = __builtin_amdgcn_mfma_f32_16x16x32_bf16(kf1, qa1, sa[n], 0, 0, 0);
            sb[n] = __builtin_amdgcn_mfma_f32_16x16x32_bf16(kf0, qb0, zero4, 0, 0, 0);
            sb[n] = __builtin_amdgcn_mfma_f32_16x16x32_bf16(kf1, qb1, sb[n], 0, 0, 0);
        }
        __builtin_amdgcn_s_setprio(0);

        // ---- softmax A (sa dies into pa), then softmax B ----
        bf16x8 pa0, pa1, pb0, pb1;
        {
            float u0 = fmaxf(fmaxf(sa[0][0], sa[0][1]), fmaxf(sa[0][2], sa[0][3]));
            float u1 = fmaxf(fmaxf(sa[1][0], sa[1][1]), fmaxf(sa[1][2], sa[1][3]));
            float u2 = fmaxf(fmaxf(sa[2][0], sa[2][1]), fmaxf(sa[2][2], sa[2][3]));
            float u3 = fmaxf(fmaxf(sa[3][0], sa[3][1]), fmaxf(sa[3][2], sa[3][3]));
            float mt = fmaxf(fmaxf(u0, u1), fmaxf(u2, u3));
            mt = fmaxf(mt, __shfl_xor(mt, 16));
            mt = fmaxf(mt, __shfl_xor(mt, 32));
            if (!__all(mt - m_a <= 8.0f)) {
                float mnew = fmaxf(m_a, mt);
                float scl = __builtin_amdgcn_exp2f(m_a - mnew);
                m_a = mnew; l_a *= scl;
#pragma unroll
                for (int dn = 0; dn < 4; dn++)
#pragma unroll
                    for (int r = 0; r < 4; r++) acc_a[dn][r] *= scl;
            }
            float p[4][4];
#pragma unroll
            for (int n = 0; n < 4; n++)
#pragma unroll
                for (int r = 0; r < 4; r++) p[n][r] = __builtin_amdgcn_exp2f(sa[n][r] - m_a);
#pragma unroll
            for (int j = 0; j < 8; j++) {
                pa0[j] = (__bf16)p[j >> 2][j & 3];
                pa1[j] = (__bf16)p[2 + (j >> 2)][j & 3];
            }
        }
        {
            float u0 = fmaxf(fmaxf(sb[0][0], sb[0][1]), fmaxf(sb[0][2], sb[0][3]));
            float u1 = fmaxf(fmaxf(sb[1][0], sb[1][1]), fmaxf(sb[1][2], sb[1][3]));
            float u2 = fmaxf(fmaxf(sb[2][0], sb[2][1]), fmaxf(sb[2][2], sb[2][3]));
            float u3 = fmaxf(fmaxf(sb[3][0], sb[3][1]), fmaxf(sb[3][2], sb[3][3]));
            float mt = fmaxf(fmaxf(u0, u1), fmaxf(u2, u3));
            mt = fmaxf(mt, __shfl_xor(mt, 16));
            mt = fmaxf(mt, __shfl_xor(mt, 32));
            if (!__all(mt - m_b <= 8.0f)) {
                float mnew = fmaxf(m_b, mt);
                float scl = __builtin_amdgcn_exp2f(m_b - mnew);
                m_b = mnew; l_b *= scl;
#pragma unroll
                for (int dn = 0; dn < 4; dn++)
#pragma unroll
                    for (int r = 0; r < 4; r++) acc_b[dn][r] *= scl;
            }
            float p[4][4];
#pragma unroll
            for (int n = 0; n < 4; n++)
#pragma unroll
                for (int r = 0; r < 4; r++) p[n][r] = __builtin_amdgcn_exp2f(sb[n][r] - m_b);
#pragma unroll
            for (int j = 0; j < 8; j++) {
                pb0[j] = (__bf16)p[j >> 2][j & 3];
                pb1[j] = (__bf16)p[2 + (j >> 2)][j & 3];
            }
        }

        // ---- PV + l-sum cluster ----
        f32x4 la = zero4, lb = zero4;
        __builtin_amdgcn_s_setprio(1);
#pragma unroll
        for (int ks = 0; ks < 2; ks++) {
            bf16x8 pA = ks ? pa1 : pa0;
            bf16x8 pB = ks ? pb1 : pb0;
#pragma unroll
            for (int dn = 0; dn < 4; dn++) {
                bf16x8 vf = *reinterpret_cast<const bf16x8*>(&Vf[cur][dn * 2 + ks][lane][0]);
                acc_a[dn] = __builtin_amdgcn_mfma_f32_16x16x32_bf16(vf, pA, acc_a[dn], 0, 0, 0);
                acc_b[dn] = __builtin_amdgcn_mfma_f32_16x16x32_bf16(vf, pB, acc_b[dn], 0, 0, 0);
            }
        }
        la = __builtin_amdgcn_mfma_f32_16x16x32_bf16(ones8, pa0, la, 0, 0, 0);
        la = __builtin_amdgcn_mfma_f32_16x16x32_bf16(ones8, pa1, la, 0, 0, 0);
        lb = __builtin_amdgcn_mfma_f32_16x16x32_bf16(ones8, pb0, lb, 0, 0, 0);
        lb = __builtin_amdgcn_mfma_f32_16x16x32_bf16(ones8, pb1, lb, 0, 0, 0);
        __builtin_amdgcn_s_setprio(0);
        l_a += la[0];
        l_b += lb[0];

        // ---- stage next tile into the other buffer; ONE barrier per tile ----
        if (kt + 1 < NT) stage_write(cur ^ 1);
        __syncthreads();
        cur ^= 1;
    }

    // normalize and write O: lane holds O[q = l15][d = dn*16 + g*4 + r]
    float inv_a = 1.0f / l_a;
    float inv_b = 1.0f / l_b;
    unsigned short* oA = Oa + (size_t)(b * SS + qA + l15) * HH + h * HDD;
    unsigned short* oB = oA + (size_t)16 * HH;
#pragma unroll
    for (int dn = 0; dn < 4; dn++) {
        ushort4 wa, wb;
        wa.x = f2b(acc_a[dn][0] * inv_a); wa.y = f2b(acc_a[dn][1] * inv_a);
        wa.z = f2b(acc_a[dn][2] * inv_a); wa.w = f2b(acc_a[dn][3] * inv_a);
        wb.x = f2b(acc_b[dn][0] * inv_b); wb.y = f2b(acc_b[dn][1] * inv_b);
        wb.z = f2b(acc_b[dn][2] * inv_b); wb.w = f2b(acc_b[dn][3] * inv_b);
        *reinterpret_cast<ushort4*>(oA + dn * 16 + g * 4) = wa;
        *reinterpret_cast<ushort4*>(oB + dn * 16 + g * 4) = wb;
    }
}

// ---------------- launcher ----------------
extern "C" void kernel_launch(void* const* d_in, const int* in_sizes, int n_in,
                              void* d_out, int out_size, void* d_ws, size_t ws_size,
                              hipStream_t stream) {
    const float* x  = (const float*)d_in[0];
    const float* Wq = (const float*)d_in[1];
    const float* bq = (const float*)d_in[2];
    const float* Wk = (const float*)d_in[3];
    const float* bk = (const float*)d_in[4];
    const float* Wv = (const float*)d_in[5];
    const float* bv = (const float*)d_in[6];
    const float* Wo = (const float*)d_in[7];
    const float* bo = (const float*)d_in[8];
    float* out = (float*)d_out;

    const int M = BB * SS;   // 8192
    const long nx = (long)M * HH;       // 8388608

    unsigned char* ws = (unsigned char*)d_ws;
    unsigned short* xb  = (unsigned short*)(ws);
    unsigned short* Wqb = (unsigned short*)(ws + 16777216);   // Wq,Wk,Wv,Wo contiguous
    unsigned short* Wob = (unsigned short*)(ws + 16777216 + 3 * 2097152);
    unsigned short* Qb  = (unsigned short*)(ws + 16777216 + 4 * 2097152);
    unsigned short* Kb  = (unsigned short*)(ws + 2 * 16777216 + 4 * 2097152);
    unsigned short* Vtb = (unsigned short*)(ws + 3 * 16777216 + 4 * 2097152);
    unsigned short* Ab  = (unsigned short*)(ws + 4 * 16777216 + 4 * 2097152);

    // fp32 -> bf16
    cvt_bf16<<<4096, 256, 0, stream>>>(x, xb, nx);
    cvt_w4<<<dim3(256, 4), 256, 0, stream>>>(Wq, Wk, Wv, Wo, Wqb);

    // fused QKV projection: N = 3072, 1536 wgs, XCD-chunked 16x12
    gemm_qkv<<<1536, 256, 0, stream>>>(xb, Wqb, bq, bk, bv, Qb, Kb, Vtb);

    // attention: 1024 wgs, XCD-chunked
    attn_kernel<<<1024, 256, 0, stream>>>(Qb, Kb, Vtb, Ab);

    // out-projection: 512 wgs, XCD-chunked 8x8
    gemm_out<<<512, 256, 0, stream>>>(Ab, Wob, bo, out, M, HH, HH);
}